// Round 2
// baseline (141.602 us; speedup 1.0000x reference)
//
#include <hip/hip_runtime.h>
#include <stdint.h>

// Problem constants (fixed by reference)
#define NTOK 8192
#define DM   1024
#define NE   8
#define NR   16
#define KX   1152   // DM + NE*NR = 1024 + 128

typedef short bf16x8 __attribute__((ext_vector_type(8)));
typedef float f32x4  __attribute__((ext_vector_type(4)));

__device__ __forceinline__ unsigned short f2bf(float f) {
    union { float f; unsigned u; } v; v.f = f;
    unsigned r = v.u + 0x7fffu + ((v.u >> 16) & 1u);   // RNE
    return (unsigned short)(r >> 16);
}

__device__ __forceinline__ void gld16(const void* g, void* l) {
    __builtin_amdgcn_global_load_lds((__attribute__((address_space(1))) void*)g,
                                     (__attribute__((address_space(3))) void*)l,
                                     16, 0, 0);
}

// ---------------------------------------------------------------------------
// prep2: tiny weight-prep kernel (off critical path, ~7 MB traffic).
//  blocks [0,1024):     WBext[j][0:1152] = [W_base[j][:] | B[:, j]]  (bf16)
//  blocks [1024,1152):  At[p][0:1024] = A[e][:][r] transpose         (bf16)
// ---------------------------------------------------------------------------
__global__ __launch_bounds__(256) void prep2(const float* __restrict__ Bsrc,
                                             const float* __restrict__ Wb,
                                             const float* __restrict__ Asrc,
                                             unsigned short* __restrict__ WBext,
                                             unsigned short* __restrict__ At) {
    const int b = blockIdx.x;
    const int t = threadIdx.x;
    if (b < 1024) {
        const int j = b;
        unsigned short* row = WBext + (size_t)j * KX;
        float4 v = ((const float4*)(Wb + (size_t)j * DM))[t];
        ushort4 o;
        o.x = f2bf(v.x); o.y = f2bf(v.y); o.z = f2bf(v.z); o.w = f2bf(v.w);
        *(ushort4*)(row + t * 4) = o;
        if (t < 128) row[DM + t] = f2bf(Bsrc[(size_t)t * DM + j]);   // B[e][r][j]
    } else {
        const int p = b - 1024;           // 0..127
        const int e = p >> 4, r = p & 15;
        for (int d = t; d < DM; d += 256)
            At[(size_t)p * DM + d] = f2bf(Asrc[e * (DM * NR) + d * NR + r]);
    }
}

// ---------------------------------------------------------------------------
// gate_hall: fused gating + x->bf16 + H = (x @ At^T) * combine.
//   512 blocks x 256 threads; 16 tokens per block; K streamed in 64-chunks,
//   double-buffered (xt 2 KB reg-staged+converted, At 16 KB via gld16).
//   fp32 gating dots accumulated DURING staging; top-2 softmax + H scaling
//   fully in-block, no combine buffer, x read from HBM exactly once.
//   Per buffer: xt[16][64] bf16 (2 KB) | At[128][64] bf16 (16 KB) = 18 KB.
//   (R1 fix: At staged at byte offset 2048 within buffer, not 4096 — the
//    4096 variant overflowed the 36 KB LDS allocation and aliased buf1's xt.)
// ---------------------------------------------------------------------------
__global__ __launch_bounds__(256) void gate_hall(const float* __restrict__ x,
                                                 const float* __restrict__ Wg,
                                                 const unsigned short* __restrict__ At,
                                                 unsigned short* __restrict__ Xext) {
    __shared__ __align__(16) unsigned short lds[18432];   // 2 x 18 KB = 36 KB
    const int t = threadIdx.x;
    const int lane = t & 63;
    const int w = t >> 6;
    const int quad = lane >> 4;
    const int l15 = lane & 15;
    const int n0 = blockIdx.x * 16;

    // staging decomposition
    const int row  = t >> 4;        // 0..15  (token row within tile)
    const int kseg = t & 15;        // float4 index within 64-elem chunk
    const int xsw  = ((kseg >> 1) ^ (row & 7)) * 8 + (kseg & 1) * 4;  // xt swizzled ushort off
    const int brow = lane >> 3;                  // 0..7 (row within 8-row gld16 issue)
    const int bseg = (lane & 7) ^ brow;          // XOR swizzle (global side)

    const float4* gx = (const float4*)(x + (size_t)(n0 + row) * DM);
    unsigned short* gxb = Xext + (size_t)(n0 + row) * KX;

    float gacc[NE] = {};
    f32x4 acc[2] = {};   // H tiles jt = 2w, 2w+1 -> cols 32w + jf*16 + l15

    // stage chunk k0 into buffer s; also: fp32 gating partial + bf16 x writeback
    #define GH_STAGE(k0, s)                                                         \
        {                                                                           \
            _Pragma("unroll")                                                       \
            for (int i = 0; i < 4; ++i) {                                           \
                const int q = w * 4 + i;                                            \
                gld16(At + (size_t)(q * 8 + brow) * DM + (k0) + bseg * 8,           \
                      (char*)lds + (s) * 18432 + 2048 + q * 1024 + lane * 16);      \
            }                                                                       \
            float4 xv = gx[((k0) >> 2) + kseg];                                     \
            ushort4 xo;                                                             \
            xo.x = f2bf(xv.x); xo.y = f2bf(xv.y);                                   \
            xo.z = f2bf(xv.z); xo.w = f2bf(xv.w);                                   \
            *(ushort4*)&lds[(s) * 9216 + row * 64 + xsw] = xo;                      \
            *(ushort4*)(gxb + (k0) + kseg * 4) = xo;                                \
            _Pragma("unroll")                                                       \
            for (int e = 0; e < NE; ++e) {                                          \
                float4 gv = ((const float4*)(Wg + (size_t)e * DM))[((k0) >> 2) + kseg]; \
                gacc[e] += xv.x * gv.x + xv.y * gv.y + xv.z * gv.z + xv.w * gv.w;   \
            }                                                                       \
        }

    #define GH_COMPUTE(s)                                                           \
        {                                                                           \
            const int xo_ = (s) * 9216, bo_ = (s) * 9216 + 1024;                    \
            _Pragma("unroll")                                                       \
            for (int kk = 0; kk < 2; ++kk) {                                        \
                const int gs = kk * 4 + quad;                                       \
                bf16x8 a = *(const bf16x8*)&lds[xo_ + l15 * 64 + (gs ^ (l15 & 7)) * 8]; \
                _Pragma("unroll")                                                   \
                for (int jf = 0; jf < 2; ++jf) {                                    \
                    const int r = (w * 2 + jf) * 16 + l15;                          \
                    bf16x8 bb = *(const bf16x8*)&lds[bo_ + r * 64 + (gs ^ (r & 7)) * 8]; \
                    acc[jf] = __builtin_amdgcn_mfma_f32_16x16x32_bf16(a, bb, acc[jf], 0, 0, 0); \
                }                                                                   \
            }                                                                       \
        }

    GH_STAGE(0, 0);
    for (int k0 = 0; k0 < DM; k0 += 128) {      // 8 macro-iters (16 chunks)
        __syncthreads();
        GH_STAGE(k0 + 64, 1);                   // max k0+64 = 960, valid
        GH_COMPUTE(0);
        __syncthreads();
        if (k0 + 128 < DM) { GH_STAGE(k0 + 128, 0); }
        GH_COMPUTE(1);
    }
    #undef GH_STAGE
    #undef GH_COMPUTE

    // ---- gating finish: reduce fp32 partials across the 16 lanes of each row
    #pragma unroll
    for (int off = 1; off <= 8; off <<= 1) {
        #pragma unroll
        for (int e = 0; e < NE; ++e) gacc[e] += __shfl_xor(gacc[e], off, 64);
    }
    // top-2, lowest index wins ties (matches lax.top_k)
    float best = gacc[0]; int bi = 0;
    #pragma unroll
    for (int e = 1; e < NE; ++e) if (gacc[e] > best) { best = gacc[e]; bi = e; }
    float sec = -1e30f; int si = 0;
    #pragma unroll
    for (int e = 0; e < NE; ++e) if (e != bi && gacc[e] > sec) { sec = gacc[e]; si = e; }
    const float ed = __expf(sec - best);
    const float w0 = 1.f / (1.f + ed);
    const float w1 = ed * w0;

    // share per-token (w0,w1,bi,si) across waves via LDS
    __syncthreads();
    float* gsh = (float*)lds;
    int*   ish = (int*)(gsh + 32);
    if (kseg == 0) {
        gsh[row] = w0; gsh[16 + row] = w1;
        ish[row] = bi; ish[16 + row] = si;
    }
    __syncthreads();

    // ---- epilogue: scale H by combine weight, write bf16
    #pragma unroll
    for (int jf = 0; jf < 2; ++jf) {
        const int jt = w * 2 + jf;              // expert index = H tile index
        #pragma unroll
        for (int v = 0; v < 4; ++v) {
            const int r = quad * 4 + v;         // token row 0..15
            const float sw0 = gsh[r], sw1 = gsh[16 + r];
            const int   sbi = ish[r], ssi = ish[16 + r];
            const float scale = (jt == sbi) ? sw0 : ((jt == ssi) ? sw1 : 0.f);
            Xext[(size_t)(n0 + r) * KX + DM + jt * 16 + l15] = f2bf(acc[jf][v] * scale);
        }
    }
}

// ---------------------------------------------------------------------------
// mgemm: out[8192][1024] = Xext[8192][1152] @ WBext[1024][1152]^T + bias
//   128x128 tile, BK=64 double-buffered (A0|B0|A1|B1 = 4x16 KB = 64 KB),
//   SINGLE barrier per K-chunk: stage(k+1) issued post-barrier, compute(k)
//   hides the load latency. XOR-swizzled K-segments, LDS-transpose epilogue,
//   XCD-aware block decode.  (unchanged from the 128.5 us version)
// ---------------------------------------------------------------------------
__global__ __launch_bounds__(256, 2) void mgemm(const unsigned short* __restrict__ Xext,
                                                const unsigned short* __restrict__ WBext,
                                                const float* __restrict__ bias,
                                                float* __restrict__ out) {
    __shared__ __align__(16) unsigned short lds[32768];   // 64 KB
    const int t = threadIdx.x;
    const int lane = t & 63;
    const int w = t >> 6;
    const int quad = lane >> 4;
    const int l15 = lane & 15;

    const int bid = blockIdx.x;          // 512
    const int xcd = bid & 7;
    const int loc = bid >> 3;
    const int bm = xcd * 8 + (loc & 7);  // 0..63
    const int bn = loc >> 3;             // 0..7

    const int wm = (w & 1) * 64;
    const int wn = (w >> 1) * 64;

    f32x4 acc[4][4] = {};

    const int srow = t >> 3;                     // 0..31
    const int seg  = (t & 7) ^ (srow & 7);       // XOR swizzle (global side)
    const unsigned short* gA = Xext  + (size_t)(bm * 128 + srow) * KX + seg * 8;
    const unsigned short* gB = WBext + (size_t)(bn * 128 + srow) * KX + seg * 8;

    #define MG_STAGE(k0, s)                                                          \
        _Pragma("unroll")                                                            \
        for (int c = 0; c < 4; ++c) {                                                \
            gld16(gA + (size_t)c * 32 * KX + (k0), (char*)lds + (s) * 32768 + c * 4096 + w * 1024);        \
            gld16(gB + (size_t)c * 32 * KX + (k0), (char*)lds + (s) * 32768 + 16384 + c * 4096 + w * 1024);\
        }

    #define MG_COMPUTE(s)                                                            \
        {                                                                            \
            const int ao = (s) * 16384, bo = (s) * 16384 + 8192;                     \
            _Pragma("unroll")                                                        \
            for (int kk = 0; kk < 2; ++kk) {                                         \
                const int gs = kk * 4 + quad;                                        \
                const int sw = (gs ^ (l15 & 7)) * 8;                                 \
                bf16x8 a[4], b[4];                                                   \
                _Pragma("unroll")                                                    \
                for (int i = 0; i < 4; ++i)                                          \
                    a[i] = *(const bf16x8*)&lds[ao + (wm + i * 16 + l15) * 64 + sw]; \
                _Pragma("unroll")                                                    \
                for (int j = 0; j < 4; ++j)                                          \
                    b[j] = *(const bf16x8*)&lds[bo + (wn + j * 16 + l15) * 64 + sw]; \
                _Pragma("unroll")                                                    \
                for (int i = 0; i < 4; ++i)                                          \
                    _Pragma("unroll")                                                \
                    for (int j = 0; j < 4; ++j)                                      \
                        acc[i][j] = __builtin_amdgcn_mfma_f32_16x16x32_bf16(a[i], b[j], acc[i][j], 0, 0, 0); \
            }                                                                        \
        }

    MG_STAGE(0, 0);
    for (int k0 = 0; k0 < KX; k0 += 128) {       // 9 macro-iters (18 chunks)
        __syncthreads();
        MG_STAGE(k0 + 64, 1);                    // k0+64 <= 1088 < 1152 always
        MG_COMPUTE(0);
        __syncthreads();
        if (k0 + 128 < KX) { MG_STAGE(k0 + 128, 0); }
        MG_COMPUTE(1);
    }
    #undef MG_STAGE
    #undef MG_COMPUTE

    // Epilogue: per-wave 64x64 LDS transpose -> coalesced float4 stores
    __syncthreads();
    float* lf = (float*)lds + w * 4096;
    #pragma unroll
    for (int j = 0; j < 4; ++j) {
        const float bv = bias[bn * 128 + wn + j * 16 + l15];
        #pragma unroll
        for (int i = 0; i < 4; ++i)
            #pragma unroll
            for (int v = 0; v < 4; ++v) {
                const int row_l = i * 16 + quad * 4 + v;
                const int col_s = (j * 16 + l15) ^ ((row_l & 1) << 4);
                lf[row_l * 64 + col_s] = acc[i][j][v] + bv;
            }
    }
    __builtin_amdgcn_s_waitcnt(0);
    #pragma unroll
    for (int rr = 0; rr < 16; ++rr) {
        const int row_r = rr * 4 + (lane >> 4);
        const int col4  = (lane & 15) * 4;
        const int col4s = col4 ^ ((row_r & 1) << 4);
        float4 vv = *(const float4*)&lf[row_r * 64 + col4s];
        *(float4*)&out[(size_t)(bm * 128 + wm + row_r) * DM + bn * 128 + wn + col4] = vv;
    }
}

// ---------------------------------------------------------------------------
extern "C" void kernel_launch(void* const* d_in, const int* in_sizes, int n_in,
                              void* d_out, int out_size, void* d_ws, size_t ws_size,
                              hipStream_t stream) {
    const float* x  = (const float*)d_in[0];   // [8192,1024]
    const float* Wg = (const float*)d_in[1];   // [8,1024]
    const float* A  = (const float*)d_in[2];   // [8,1024,16]
    const float* B  = (const float*)d_in[3];   // [8,16,1024]
    const float* Wb = (const float*)d_in[4];   // [1024,1024]
    const float* bb = (const float*)d_in[5];   // [1024]
    float* out = (float*)d_out;

    char* ws = (char*)d_ws;
    unsigned short* Xext  = (unsigned short*)ws;                            // 18874368 B
    unsigned short* WBext = (unsigned short*)(ws + 18874368);               // 2359296 B
    unsigned short* At    = (unsigned short*)(ws + 18874368 + 2359296);     // 262144 B

    hipLaunchKernelGGL(prep2,     dim3(1152), dim3(256), 0, stream, B, Wb, A, WBext, At);
    hipLaunchKernelGGL(gate_hall, dim3(512),  dim3(256), 0, stream, x, Wg, At, Xext);
    hipLaunchKernelGGL(mgemm,     dim3(512),  dim3(256), 0, stream, Xext, WBext, bb, out);
}

// Round 3
// 129.796 us; speedup vs baseline: 1.0910x; 1.0910x over previous
//
#include <hip/hip_runtime.h>
#include <stdint.h>

// Problem constants (fixed by reference)
#define NTOK 8192
#define DM   1024
#define NE   8
#define NR   16
#define KX   1152   // DM + NE*NR = 1024 + 128

typedef short bf16x8 __attribute__((ext_vector_type(8)));
typedef float f32x4  __attribute__((ext_vector_type(4)));

__device__ __forceinline__ unsigned short f2bf(float f) {
    union { float f; unsigned u; } v; v.f = f;
    unsigned r = v.u + 0x7fffu + ((v.u >> 16) & 1u);   // RNE
    return (unsigned short)(r >> 16);
}

__device__ __forceinline__ void gld16(const void* g, void* l) {
    __builtin_amdgcn_global_load_lds((__attribute__((address_space(1))) void*)g,
                                     (__attribute__((address_space(3))) void*)l,
                                     16, 0, 0);
}

#define VM_WAIT(n) asm volatile("s_waitcnt vmcnt(" #n ")" ::: "memory")
#define BAR() __builtin_amdgcn_s_barrier()

// ---------------------------------------------------------------------------
// prep: fused role-by-block kernel (R0-proven, 128.5us config).
//  blocks [0,2048):     fp32 gating (wave/token) + x -> bf16 into Xext[:,0:1024]
//  blocks [2048,3072):  WBext[j][0:1152] = [W_base[j][:] | B[:, j]]  (bf16)
//  blocks [3072,3200):  At[p][0:1024] = A[e][:][r] transpose        (bf16)
// ---------------------------------------------------------------------------
__global__ __launch_bounds__(256) void prep(const float* __restrict__ x,
                                            const float* __restrict__ Wg,
                                            const float* __restrict__ Asrc,
                                            const float* __restrict__ Bsrc,
                                            const float* __restrict__ Wb,
                                            float* __restrict__ combine,
                                            unsigned short* __restrict__ Xext,
                                            unsigned short* __restrict__ WBext,
                                            unsigned short* __restrict__ At) {
    const int b = blockIdx.x;
    const int t = threadIdx.x;

    if (b < 2048) {
        const int lane = t & 63;
        const int w = t >> 6;
        const int n = b * 4 + w;

        const float4* x4 = (const float4*)(x + (size_t)n * DM);
        float4 xv[4];
        #pragma unroll
        for (int i = 0; i < 4; ++i) xv[i] = x4[i * 64 + lane];

        float acc[NE];
        #pragma unroll
        for (int e = 0; e < NE; ++e) {
            const float4* wg4 = (const float4*)(Wg + (size_t)e * DM);
            float s = 0.f;
            #pragma unroll
            for (int i = 0; i < 4; ++i) {
                float4 g = wg4[i * 64 + lane];
                s += xv[i].x * g.x + xv[i].y * g.y + xv[i].z * g.z + xv[i].w * g.w;
            }
            acc[e] = s;
        }
        #pragma unroll
        for (int off = 32; off >= 1; off >>= 1) {
            #pragma unroll
            for (int e = 0; e < NE; ++e) acc[e] += __shfl_xor(acc[e], off, 64);
        }
        // top-2, lowest index wins ties (matches lax.top_k)
        float best = acc[0]; int bi = 0;
        #pragma unroll
        for (int e = 1; e < NE; ++e) if (acc[e] > best) { best = acc[e]; bi = e; }
        float sec = -1e30f; int si = 0;
        #pragma unroll
        for (int e = 0; e < NE; ++e) if (e != bi && acc[e] > sec) { sec = acc[e]; si = e; }
        const float ed = __expf(sec - best);
        const float w0 = 1.f / (1.f + ed);
        const float w1 = ed * w0;
        if (lane < NE)
            combine[n * NE + lane] = (lane == bi) ? w0 : ((lane == si) ? w1 : 0.f);

        unsigned short* xrow = Xext + (size_t)n * KX;
        #pragma unroll
        for (int i = 0; i < 4; ++i) {
            ushort4 o;
            o.x = f2bf(xv[i].x); o.y = f2bf(xv[i].y);
            o.z = f2bf(xv[i].z); o.w = f2bf(xv[i].w);
            *(ushort4*)(xrow + (i * 64 + lane) * 4) = o;
        }
    } else if (b < 3072) {
        const int j = b - 2048;
        unsigned short* row = WBext + (size_t)j * KX;
        float4 v = ((const float4*)(Wb + (size_t)j * DM))[t];
        ushort4 o;
        o.x = f2bf(v.x); o.y = f2bf(v.y); o.z = f2bf(v.z); o.w = f2bf(v.w);
        *(ushort4*)(row + t * 4) = o;
        if (t < 128) row[DM + t] = f2bf(Bsrc[(size_t)t * DM + j]);   // B[e][r][j]
    } else {
        const int p = b - 3072;
        const int e = p >> 4, r = p & 15;
        for (int d = t; d < DM; d += 256)
            At[(size_t)p * DM + d] = f2bf(Asrc[e * (DM * NR) + d * NR + r]);
    }
}

// ---------------------------------------------------------------------------
// hall: Hfull = (x_bf16 @ At^T) * combine -> bf16 into Xext[:, 1024:1152]
//   512 blocks (32 tokens x 64 cols -> 2 blocks/CU).
//   R3 change (T4-lite): counted vmcnt(3) + raw barriers instead of
//   __syncthreads()'s vmcnt(0) drain — each stage now has a FULL iteration
//   (compute + 2 barriers + next issue) to land instead of one compute phase.
//   Per chunk c: [vmcnt(S(c) done)] [bar] [compute c] [bar] [stage c+2].
// ---------------------------------------------------------------------------
__global__ __launch_bounds__(256) void hall_kernel(unsigned short* Xext,
                                                   const unsigned short* __restrict__ At,
                                                   const float* __restrict__ combine) {
    // per buffer: xt 32x64 bf16 (4 KB) + at 64x64 bf16 (8 KB) = 12 KB; x2 = 24 KB
    __shared__ __align__(16) unsigned short lds[12288];
    const int t = threadIdx.x;
    const int lane = t & 63;
    const int w = t >> 6;
    const int quad = lane >> 4;
    const int l15 = lane & 15;
    const int bid = blockIdx.x;        // 512
    const int bm = bid >> 1;           // token tile 0..255
    const int cb = bid & 1;            // column half 0..1
    const int n0 = bm * 32;
    const int wm = (w & 1) * 16;
    const int wn = (w >> 1) * 32;

    const int srow = t >> 3;                     // 0..31
    const int seg  = (t & 7) ^ (srow & 7);       // XOR swizzle (global side)

    const unsigned short* gX  = Xext + (size_t)(n0 + srow) * KX + seg * 8;
    const unsigned short* gA0 = At + (size_t)(cb * 64 + srow) * DM + seg * 8;
    const unsigned short* gA1 = At + (size_t)(cb * 64 + 32 + srow) * DM + seg * 8;

    f32x4 acc[2] = {};

    // stage(k0, buf s): x -> [s*12KB, +4KB), At -> [s*12KB+4KB, +8KB)  (3 gld16/thread)
    #define HALL_STAGE(k0, s)                                              \
        gld16(gX  + (k0), (char*)lds + (s) * 12288 + w * 1024);            \
        gld16(gA0 + (k0), (char*)lds + (s) * 12288 + 4096 + w * 1024);     \
        gld16(gA1 + (k0), (char*)lds + (s) * 12288 + 8192 + w * 1024);

    #define HALL_COMPUTE(s)                                                        \
        {                                                                          \
            const int xo = (s) * 6144, ao = (s) * 6144 + 2048;                     \
            _Pragma("unroll")                                                      \
            for (int kk = 0; kk < 2; ++kk) {                                       \
                const int gs = kk * 4 + quad;                                      \
                const int sw = (gs ^ (l15 & 7)) * 8;                               \
                bf16x8 a = *(const bf16x8*)&lds[xo + (wm + l15) * 64 + sw];        \
                _Pragma("unroll")                                                  \
                for (int jf = 0; jf < 2; ++jf) {                                   \
                    bf16x8 bb = *(const bf16x8*)&lds[ao + (wn + jf * 16 + l15) * 64 + sw]; \
                    acc[jf] = __builtin_amdgcn_mfma_f32_16x16x32_bf16(a, bb, acc[jf], 0, 0, 0); \
                }                                                                  \
            }                                                                      \
        }

    HALL_STAGE(0, 0);
    HALL_STAGE(64, 1);
    for (int k0 = 0; k0 < DM; k0 += 128) {       // 8 macro-iters (16 chunks)
        VM_WAIT(3);                               // S(k0) landed (S(k0+64)'s 3 remain)
        BAR();
        HALL_COMPUTE(0);
        BAR();                                    // all waves done reading buf0
        if (k0 + 128 < DM) {
            HALL_STAGE(k0 + 128, 0);
            VM_WAIT(3);                           // S(k0+64) landed
        } else {
            VM_WAIT(0);                           // tail: S(k0+64) is the only one left
        }
        BAR();
        HALL_COMPUTE(1);
        BAR();                                    // all waves done reading buf1
        if (k0 + 192 < DM) HALL_STAGE(k0 + 192, 1);
    }

    // Epilogue: scale by combine, write bf16 H
    #pragma unroll
    for (int jf = 0; jf < 2; ++jf) {
        const int p = cb * 64 + wn + jf * 16 + l15;
        const int e = p >> 4;
        #pragma unroll
        for (int v = 0; v < 4; ++v) {
            const int n = n0 + wm + quad * 4 + v;
            const float val = acc[jf][v] * combine[n * NE + e];
            Xext[(size_t)n * KX + DM + p] = f2bf(val);
        }
    }
    #undef HALL_STAGE
    #undef HALL_COMPUTE
}

// ---------------------------------------------------------------------------
// mgemm: out[8192][1024] = Xext[8192][1152] @ WBext[1024][1152]^T + bias
//   128x128 tile, BK=64 double-buffered (A0|B0|A1|B1 = 4x16 KB = 64 KB),
//   XOR-swizzled K-segments, LDS-transpose epilogue, XCD-aware block decode.
//   R3 change (T4-lite): counted vmcnt(8) + raw barriers — the oldest stage
//   has a full iteration in flight instead of being drained at each barrier.
// ---------------------------------------------------------------------------
__global__ __launch_bounds__(256, 2) void mgemm(const unsigned short* __restrict__ Xext,
                                                const unsigned short* __restrict__ WBext,
                                                const float* __restrict__ bias,
                                                float* __restrict__ out) {
    __shared__ __align__(16) unsigned short lds[32768];   // 64 KB
    const int t = threadIdx.x;
    const int lane = t & 63;
    const int w = t >> 6;
    const int quad = lane >> 4;
    const int l15 = lane & 15;

    const int bid = blockIdx.x;          // 512
    const int xcd = bid & 7;
    const int loc = bid >> 3;
    const int bm = xcd * 8 + (loc & 7);  // 0..63
    const int bn = loc >> 3;             // 0..7

    const int wm = (w & 1) * 64;
    const int wn = (w >> 1) * 64;

    f32x4 acc[4][4] = {};

    const int srow = t >> 3;                     // 0..31
    const int seg  = (t & 7) ^ (srow & 7);       // XOR swizzle (global side)
    const unsigned short* gA = Xext  + (size_t)(bm * 128 + srow) * KX + seg * 8;
    const unsigned short* gB = WBext + (size_t)(bn * 128 + srow) * KX + seg * 8;

    // stage(k0, s): 8 gld16/thread
    #define MG_STAGE(k0, s)                                                          \
        _Pragma("unroll")                                                            \
        for (int c = 0; c < 4; ++c) {                                                \
            gld16(gA + (size_t)c * 32 * KX + (k0), (char*)lds + (s) * 32768 + c * 4096 + w * 1024);        \
            gld16(gB + (size_t)c * 32 * KX + (k0), (char*)lds + (s) * 32768 + 16384 + c * 4096 + w * 1024);\
        }

    #define MG_COMPUTE(s)                                                            \
        {                                                                            \
            const int ao = (s) * 16384, bo = (s) * 16384 + 8192;                     \
            _Pragma("unroll")                                                        \
            for (int kk = 0; kk < 2; ++kk) {                                         \
                const int gs = kk * 4 + quad;                                        \
                const int sw = (gs ^ (l15 & 7)) * 8;                                 \
                bf16x8 a[4], b[4];                                                   \
                _Pragma("unroll")                                                    \
                for (int i = 0; i < 4; ++i)                                          \
                    a[i] = *(const bf16x8*)&lds[ao + (wm + i * 16 + l15) * 64 + sw]; \
                _Pragma("unroll")                                                    \
                for (int j = 0; j < 4; ++j)                                          \
                    b[j] = *(const bf16x8*)&lds[bo + (wn + j * 16 + l15) * 64 + sw]; \
                _Pragma("unroll")                                                    \
                for (int i = 0; i < 4; ++i)                                          \
                    _Pragma("unroll")                                                \
                    for (int j = 0; j < 4; ++j)                                      \
                        acc[i][j] = __builtin_amdgcn_mfma_f32_16x16x32_bf16(a[i], b[j], acc[i][j], 0, 0, 0); \
            }                                                                        \
        }

    MG_STAGE(0, 0);
    MG_STAGE(64, 1);
    for (int k0 = 0; k0 < KX; k0 += 128) {       // 9 macro-iters (18 chunks)
        VM_WAIT(8);                               // S(k0) landed (S(k0+64)'s 8 remain)
        BAR();
        MG_COMPUTE(0);
        BAR();                                    // all waves done reading buf0
        if (k0 + 128 < KX) {
            MG_STAGE(k0 + 128, 0);
            VM_WAIT(8);                           // S(k0+64) landed
        } else {
            VM_WAIT(0);                           // tail
        }
        BAR();
        MG_COMPUTE(1);
        BAR();                                    // all waves done reading buf1
        if (k0 + 192 < KX) MG_STAGE(k0 + 192, 1);
    }
    #undef MG_STAGE
    #undef MG_COMPUTE

    // Epilogue: per-wave 64x64 LDS transpose -> coalesced float4 stores
    __syncthreads();
    float* lf = (float*)lds + w * 4096;
    #pragma unroll
    for (int j = 0; j < 4; ++j) {
        const float bv = bias[bn * 128 + wn + j * 16 + l15];
        #pragma unroll
        for (int i = 0; i < 4; ++i)
            #pragma unroll
            for (int v = 0; v < 4; ++v) {
                const int row_l = i * 16 + quad * 4 + v;
                const int col_s = (j * 16 + l15) ^ ((row_l & 1) << 4);
                lf[row_l * 64 + col_s] = acc[i][j][v] + bv;
            }
    }
    __builtin_amdgcn_s_waitcnt(0);
    #pragma unroll
    for (int rr = 0; rr < 16; ++rr) {
        const int row_r = rr * 4 + (lane >> 4);
        const int col4  = (lane & 15) * 4;
        const int col4s = col4 ^ ((row_r & 1) << 4);
        float4 vv = *(const float4*)&lf[row_r * 64 + col4s];
        *(float4*)&out[(size_t)(bm * 128 + wm + row_r) * DM + bn * 128 + wn + col4] = vv;
    }
}

// ---------------------------------------------------------------------------
extern "C" void kernel_launch(void* const* d_in, const int* in_sizes, int n_in,
                              void* d_out, int out_size, void* d_ws, size_t ws_size,
                              hipStream_t stream) {
    const float* x  = (const float*)d_in[0];   // [8192,1024]
    const float* Wg = (const float*)d_in[1];   // [8,1024]
    const float* A  = (const float*)d_in[2];   // [8,1024,16]
    const float* B  = (const float*)d_in[3];   // [8,16,1024]
    const float* Wb = (const float*)d_in[4];   // [1024,1024]
    const float* bb = (const float*)d_in[5];   // [1024]
    float* out = (float*)d_out;

    char* ws = (char*)d_ws;
    float*          combine = (float*)ws;                                   // 262144 B
    unsigned short* Xext    = (unsigned short*)(ws + 262144);               // 18874368 B
    unsigned short* WBext   = (unsigned short*)(ws + 262144 + 18874368);    // 2359296 B
    unsigned short* At      = (unsigned short*)(ws + 262144 + 18874368 + 2359296); // 262144 B

    hipLaunchKernelGGL(prep,        dim3(3200), dim3(256), 0, stream,
                       x, Wg, A, B, Wb, combine, Xext, WBext, At);
    hipLaunchKernelGGL(hall_kernel, dim3(512),  dim3(256), 0, stream, Xext, At, combine);
    hipLaunchKernelGGL(mgemm,       dim3(512),  dim3(256), 0, stream, Xext, WBext, bb, out);
}